// Round 4
// baseline (133.983 us; speedup 1.0000x reference)
//
#include <hip/hip_runtime.h>

// Problem constants
#define EDIM 1024
#define NROW 32

constexpr int AUD_ELEMS  = 32 * 1024;          // audio_output 32x1024
constexpr int CONN_ELEMS = 1024 * 4096;        // connections copy
constexpr int INW_ELEMS  = 3 * 1024 * 1024;    // in_proj_w copy
constexpr int OUTW_ELEMS = 1024 * 1024;        // out_proj_w copy

constexpr int AUD_F4   = AUD_ELEMS / 4;        // 8192
constexpr int CONN_F4  = CONN_ELEMS / 4;       // 1048576
constexpr int INW_F4   = INW_ELEMS / 4;        // 786432
constexpr int OUTW_F4  = OUTW_ELEMS / 4;       // 262144
constexpr int TOTAL_F4 = AUD_F4 + CONN_F4 + INW_F4 + OUTW_F4;  // 2105344

// ---------------------------------------------------------------------------
// K0: output copy. Zero the audio region (K3's atomics land there), then
// verbatim copies of connections / in_proj_w / out_proj_w (STDP delta == 0
// exactly because TAU_POS == TAU_NEG). [Byte-identical to the Round-1 kernel
// that ran cleanly on this container.]
// ---------------------------------------------------------------------------
__global__ __launch_bounds__(256) void copy_zero_kernel(
    const float4* __restrict__ conn, const float4* __restrict__ inw,
    const float4* __restrict__ outw, float4* __restrict__ out)
{
    int i = blockIdx.x * 256 + threadIdx.x;
    if (i >= TOTAL_F4) return;
    float4 v;
    if (i < AUD_F4) {
        v = make_float4(0.f, 0.f, 0.f, 0.f);
    } else if (i < AUD_F4 + CONN_F4) {
        v = conn[i - AUD_F4];
    } else if (i < AUD_F4 + CONN_F4 + INW_F4) {
        v = inw[i - (AUD_F4 + CONN_F4)];
    } else {
        v = outw[i - (AUD_F4 + CONN_F4 + INW_F4)];
    }
    out[i] = v;
}

// ---------------------------------------------------------------------------
// K1/K2: C[32 x 1024] = A[32 x 1024] @ B[1024 x 1024]^T + bias.
// One wave per (e, n-group of NG); each wave keeps B row e (4 KB) in regs and
// streams NG A rows with a 2-way n unroll for load ILP; wave shuffle-reduce.
// grid*256/64 waves total; NG = 32*1024 / #waves.
// ---------------------------------------------------------------------------
template <int NG>
__global__ __launch_bounds__(256) void gemm_bt_kernel(
    const float* __restrict__ A, const float* __restrict__ B,
    const float* __restrict__ bias, float* __restrict__ C)
{
    int gw   = (blockIdx.x * 256 + threadIdx.x) >> 6;
    int lane = threadIdx.x & 63;
    int e    = gw & 1023;
    int n0   = (gw >> 10) * NG;

    const float4* Br = (const float4*)(B + (size_t)e * EDIM);
    float4 b0 = Br[lane], b1 = Br[lane + 64], b2 = Br[lane + 128], b3 = Br[lane + 192];
    float be = bias[e];
#pragma unroll
    for (int i = 0; i < NG; i += 2) {
        int n = n0 + i;
        const float4* A0 = (const float4*)(A + (size_t)n * EDIM);
        const float4* A1 = (const float4*)(A + (size_t)(n + 1) * EDIM);
        float4 x0 = A0[lane], x1 = A0[lane + 64], x2 = A0[lane + 128], x3 = A0[lane + 192];
        float4 y0 = A1[lane], y1 = A1[lane + 64], y2 = A1[lane + 128], y3 = A1[lane + 192];
        float s0 = x0.x*b0.x + x0.y*b0.y + x0.z*b0.z + x0.w*b0.w
                 + x1.x*b1.x + x1.y*b1.y + x1.z*b1.z + x1.w*b1.w
                 + x2.x*b2.x + x2.y*b2.y + x2.z*b2.z + x2.w*b2.w
                 + x3.x*b3.x + x3.y*b3.y + x3.z*b3.z + x3.w*b3.w;
        float s1 = y0.x*b0.x + y0.y*b0.y + y0.z*b0.z + y0.w*b0.w
                 + y1.x*b1.x + y1.y*b1.y + y1.z*b1.z + y1.w*b1.w
                 + y2.x*b2.x + y2.y*b2.y + y2.z*b2.z + y2.w*b2.w
                 + y3.x*b3.x + y3.y*b3.y + y3.z*b3.z + y3.w*b3.w;
#pragma unroll
        for (int off = 32; off > 0; off >>= 1) {
            s0 += __shfl_down(s0, off);
            s1 += __shfl_down(s1, off);
        }
        if (lane == 0) {
            C[(size_t)n * EDIM + e]       = s0 + be;
            C[(size_t)(n + 1) * EDIM + e] = s1 + be;
        }
    }
}

// ---------------------------------------------------------------------------
// K3: audio[32 x 1024] += attn @ connections[:, :1024].
// 256 blocks = (8 n-groups of 4) x (32 k-chunks of 32 rows). Coalesced float4
// reads of each conn row's first 4 KB; partials land via f32 atomicAdd into
// the pre-zeroed audio region (32-way contention per address).
// ---------------------------------------------------------------------------
__global__ __launch_bounds__(256) void k3_audio(
    const float* __restrict__ attn, const float* __restrict__ conn,
    float* __restrict__ out)
{
    int g  = blockIdx.x & 7;       // n-group
    int kc = blockIdx.x >> 3;      // k-chunk [0,32)
    int n0 = g * 4;
    int k0 = kc * 32;
    int t  = threadIdx.x;

    __shared__ float sa[128];      // attn[n0..n0+3][k0..k0+31]
    if (t < 128) sa[t] = attn[(size_t)(n0 + (t >> 5)) * EDIM + k0 + (t & 31)];
    __syncthreads();

    const float4* c4 = (const float4*)conn;   // 1024 float4 per 4096-col row
    float4 acc0 = {0,0,0,0}, acc1 = {0,0,0,0}, acc2 = {0,0,0,0}, acc3 = {0,0,0,0};
#pragma unroll 8
    for (int k = 0; k < 32; ++k) {
        float4 c = c4[(size_t)(k0 + k) * 1024 + t];
        float a0v = sa[k], a1v = sa[32 + k], a2v = sa[64 + k], a3v = sa[96 + k];
        acc0.x += a0v*c.x; acc0.y += a0v*c.y; acc0.z += a0v*c.z; acc0.w += a0v*c.w;
        acc1.x += a1v*c.x; acc1.y += a1v*c.y; acc1.z += a1v*c.z; acc1.w += a1v*c.w;
        acc2.x += a2v*c.x; acc2.y += a2v*c.y; acc2.z += a2v*c.z; acc2.w += a2v*c.w;
        acc3.x += a3v*c.x; acc3.y += a3v*c.y; acc3.z += a3v*c.z; acc3.w += a3v*c.w;
    }

    float* o0 = out + (size_t)(n0 + 0) * 1024 + 4 * t;
    float* o1 = out + (size_t)(n0 + 1) * 1024 + 4 * t;
    float* o2 = out + (size_t)(n0 + 2) * 1024 + 4 * t;
    float* o3 = out + (size_t)(n0 + 3) * 1024 + 4 * t;
    atomicAdd(o0 + 0, acc0.x); atomicAdd(o0 + 1, acc0.y); atomicAdd(o0 + 2, acc0.z); atomicAdd(o0 + 3, acc0.w);
    atomicAdd(o1 + 0, acc1.x); atomicAdd(o1 + 1, acc1.y); atomicAdd(o1 + 2, acc1.z); atomicAdd(o1 + 3, acc1.w);
    atomicAdd(o2 + 0, acc2.x); atomicAdd(o2 + 1, acc2.y); atomicAdd(o2 + 2, acc2.z); atomicAdd(o2 + 3, acc2.w);
    atomicAdd(o3 + 0, acc3.x); atomicAdd(o3 + 1, acc3.y); atomicAdd(o3 + 2, acc3.z); atomicAdd(o3 + 3, acc3.w);
}

extern "C" void kernel_launch(void* const* d_in, const int* in_sizes, int n_in,
                              void* d_out, int out_size, void* d_ws, size_t ws_size,
                              hipStream_t stream) {
    // setup_inputs order:
    // 0 av_value, 1 av_key, 2 av_query, 3 in_proj_w, 4 in_proj_b,
    // 5 out_proj_w, 6 out_proj_b, 7 connections
    const float* av_value   = (const float*)d_in[0];
    const float* in_proj_w  = (const float*)d_in[3];
    const float* in_proj_b  = (const float*)d_in[4];
    const float* out_proj_w = (const float*)d_in[5];
    const float* out_proj_b = (const float*)d_in[6];
    const float* conn       = (const float*)d_in[7];
    float* out = (float*)d_out;

    float* vp   = (float*)d_ws;            // 32x1024
    float* attn = vp + AUD_ELEMS;          // 32x1024

    // K0: zero audio region + verbatim weight copies (zero STDP delta)
    copy_zero_kernel<<<(TOTAL_F4 + 255) / 256, 256, 0, stream>>>(
        (const float4*)conn, (const float4*)in_proj_w,
        (const float4*)out_proj_w, (float4*)out);

    // K1: vp = av_value @ Wv^T + bv   (Wv = in_proj_w rows [2048,3072))
    //     1024 blocks -> 4096 waves -> 4 waves per e, 8 rows each
    gemm_bt_kernel<8><<<1024, 256, 0, stream>>>(
        av_value, in_proj_w + 2 * EDIM * EDIM, in_proj_b + 2 * EDIM, vp);

    // K2: attn = vp @ Wo^T + bo (softmax over size-1 axis == identity)
    //     512 blocks -> 2048 waves -> 2 waves per e, 16 rows each
    gemm_bt_kernel<16><<<512, 256, 0, stream>>>(vp, out_proj_w, out_proj_b, attn);

    // K3: audio = attn @ connections[:, :1024]
    k3_audio<<<256, 256, 0, stream>>>(attn, conn, out);
}